// Round 4
// baseline (311.812 us; speedup 1.0000x reference)
//
#include <hip/hip_runtime.h>
#include <hip/hip_bf16.h>
#include <math.h>

#define NB   64      // batch
#define D2   64      // objects per batch
#define OBJ  26      // K+2 features per object
#define NQST 11
#define HID  256
#define NOUT 28
#define NTILE 32     // p-tiles per batch (2 p's each, processed sequentially)

typedef __attribute__((ext_vector_type(8))) short s16x8;
typedef __attribute__((ext_vector_type(4))) float f32x4;
typedef __attribute__((ext_vector_type(2))) unsigned int u32x2;

__device__ __forceinline__ unsigned short f2bf(float f) {
    union { float f; unsigned u; } v; v.f = f;
    unsigned r = v.u + 0x7FFFu + ((v.u >> 16) & 1u);
    return (unsigned short)(r >> 16);
}
__device__ __forceinline__ float bf2f(unsigned short h) {
    union { unsigned u; float f; } v; v.u = ((unsigned)h) << 16;
    return v.f;
}
__device__ __forceinline__ unsigned pack_bf2(float a, float b) {
    return ((unsigned)f2bf(a)) | (((unsigned)f2bf(b)) << 16);
}

// ---------------------------------------------------------------------------
// Kernel 1: per-batch A[q][n], B[p][n] (bf16) from the g1 decomposition.
//   A[q] = o[q] @ g1_w[0:26]
//   B[p] = o[p] @ g1_w[26:52] + qst @ g1_w[52:63] + g1_b
// ---------------------------------------------------------------------------
__global__ __launch_bounds__(256) void prep_kernel(
        const float* __restrict__ x, const float* __restrict__ qst,
        const float* __restrict__ g1_w, const float* __restrict__ g1_b,
        unsigned short* __restrict__ Abf, unsigned short* __restrict__ Bbf) {
    int b = blockIdx.x;
    int tid = threadIdx.x;
    __shared__ float o_lds[D2][OBJ];
    for (int idx = tid; idx < 24 * D2; idx += 256) {
        int c = idx >> 6, pos = idx & 63;
        o_lds[pos][c] = x[(b * 24 + c) * D2 + pos];
    }
    if (tid < D2) {
        o_lds[tid][24] = (float)(tid & 7) * (8.0f / 7.0f) - 4.0f;  // cx = coords[col]
        o_lds[tid][25] = (float)(tid >> 3) * (8.0f / 7.0f) - 4.0f; // cy = coords[row]
    }
    __syncthreads();
    int n = tid;  // 0..255
    float qpart = g1_b[n];
    for (int s = 0; s < NQST; ++s)
        qpart += qst[b * NQST + s] * g1_w[(2 * OBJ + s) * HID + n];
    for (int q0 = 0; q0 < D2; q0 += 16) {
        float accA[16], accB[16];
        #pragma unroll
        for (int i = 0; i < 16; ++i) { accA[i] = 0.f; accB[i] = 0.f; }
        for (int c = 0; c < OBJ; ++c) {
            float wA = g1_w[c * HID + n];
            float wB = g1_w[(OBJ + c) * HID + n];
            #pragma unroll
            for (int i = 0; i < 16; ++i) {
                float ov = o_lds[q0 + i][c];
                accA[i] += ov * wA;
                accB[i] += ov * wB;
            }
        }
        #pragma unroll
        for (int i = 0; i < 16; ++i) {
            int q = q0 + i;
            Abf[(b * D2 + q) * HID + n] = f2bf(accA[i]);
            Bbf[(b * D2 + q) * HID + n] = f2bf(accB[i] + qpart);
        }
    }
}

// ---------------------------------------------------------------------------
// Kernel 2: convert+transpose g2/g3/g4 weights: Wt[l][n][k] = W_l[k][n] (bf16)
// ---------------------------------------------------------------------------
__global__ __launch_bounds__(256) void wconv_kernel(
        const float* __restrict__ g2_w, const float* __restrict__ g3_w,
        const float* __restrict__ g4_w, unsigned short* __restrict__ Wt) {
    int l = blockIdx.x >> 8;
    int n = blockIdx.x & 255;
    const float* W = (l == 0) ? g2_w : ((l == 1) ? g3_w : g4_w);
    int k = threadIdx.x;
    Wt[(l * HID + n) * HID + k] = f2bf(W[k * HID + n]);
}

// ---------------------------------------------------------------------------
// Kernel 3: main fused g-network.
// 256 threads = 4 waves; per WG: batch b, tile t, 2 p's sequential, M=64 tile.
// Each wave owns a 64-col n-slice: acc[4][4] = 64 regs; live set ~96 < 128 cap
// -> 4 blocks/CU (32 KiB LDS each), waves on a SIMD come from different
// blocks so barrier stalls overlap.
// Layers 0,1 use SWAPPED operands mfma(W,h) -> D[n][m]: per-lane 4 consecutive
// n at fixed m -> packed ds_write_b64 epilogue (16 writes vs 32 b16).
// Layer 2 unswapped -> in-lane pair-sum + 2 shuffles.
// ---------------------------------------------------------------------------
__global__ __launch_bounds__(256, 4) void rn_main(
        const unsigned short* __restrict__ Abf, const unsigned short* __restrict__ Bbf,
        const unsigned short* __restrict__ Wt,
        const float* __restrict__ g2_b, const float* __restrict__ g3_b,
        const float* __restrict__ g4_b, float* __restrict__ partial) {
    // XCD-aware swizzle: 2048 WGs, 8 XCDs (2048 % 8 == 0 -> bijective)
    int wg = blockIdx.x;
    int swz = (wg & 7) * 256 + (wg >> 3);
    int b = swz >> 5;
    int t = swz & 31;

    __shared__ unsigned short h_lds[D2 * HID];   // 32 KiB

    int tid = threadIdx.x;   // 0..255
    int lane = tid & 63;
    int wid = tid >> 6;      // wave 0..3 -> n-slice of 64
    int rg = lane >> 4;      // 0..3
    int col = lane & 15;

    const unsigned short* Ab = Abf + (size_t)(b * D2) * HID;

    float pacc[4] = {0.f, 0.f, 0.f, 0.f};

    for (int pp = 0; pp < 2; ++pp) {
        const unsigned short* Bb = Bbf + (size_t)(b * D2 + t * 2 + pp) * HID;

        // ---- layer 1 staging: h[m][k] = relu(A[q=m][k] + B[p][k]) ----
        #pragma unroll
        for (int i = 0; i < 8; ++i) {
            int c = tid + i * 256;       // 2048 chunks of 8 bf16
            int m = c >> 5;              // 0..63
            int k0 = (c & 31) * 8;
            s16x8 av = *(const s16x8*)(Ab + m * HID + k0);
            s16x8 bv = *(const s16x8*)(Bb + k0);
            s16x8 hv;
            #pragma unroll
            for (int j = 0; j < 8; ++j) {
                float f = bf2f((unsigned short)av[j]) + bf2f((unsigned short)bv[j]);
                f = f > 0.f ? f : 0.f;
                hv[j] = (short)f2bf(f);
            }
            int byte = (m * 512 + k0 * 2) ^ ((m & 7) << 4);
            *(s16x8*)((char*)h_lds + byte) = hv;
        }
        __syncthreads();

        // ---- layers 0,1: swapped-operand MFMA, packed in-place writeback ----
        for (int layer = 0; layer < 2; ++layer) {
            const unsigned short* Wl = Wt + (size_t)layer * HID * HID
                                          + (size_t)(wid * 64) * HID;
            const float* bias = (layer == 0) ? g2_b : g3_b;

            f32x4 acc[4][4];   // [nf][mf]
            #pragma unroll
            for (int nf = 0; nf < 4; ++nf)
                #pragma unroll
                for (int mf = 0; mf < 4; ++mf)
                    acc[nf][mf] = (f32x4){0.f, 0.f, 0.f, 0.f};

            #pragma unroll 2
            for (int ks = 0; ks < 8; ++ks) {
                int ko = ks * 32 + rg * 8;   // k element base for this lane
                s16x8 wfr[4];
                #pragma unroll
                for (int nf = 0; nf < 4; ++nf)
                    wfr[nf] = *(const s16x8*)(Wl + (nf * 16 + col) * HID + ko);
                s16x8 hfr[4];
                #pragma unroll
                for (int mf = 0; mf < 4; ++mf) {
                    int m = mf * 16 + col;
                    int byte = (m * 512 + ko * 2) ^ ((m & 7) << 4);
                    hfr[mf] = *(const s16x8*)((const char*)h_lds + byte);
                }
                #pragma unroll
                for (int nf = 0; nf < 4; ++nf)
                    #pragma unroll
                    for (int mf = 0; mf < 4; ++mf)
                        acc[nf][mf] = __builtin_amdgcn_mfma_f32_16x16x32_bf16(
                            wfr[nf], hfr[mf], acc[nf][mf], 0, 0, 0);
            }
            __syncthreads();   // every wave has read all of h

            // epilogue: D[n][m]: n = wid*64+nf*16+rg*4+r, m = mf*16+col
            #pragma unroll
            for (int nf = 0; nf < 4; ++nf) {
                int n0 = wid * 64 + nf * 16 + rg * 4;
                f32x4 b4 = *(const f32x4*)(bias + n0);
                #pragma unroll
                for (int mf = 0; mf < 4; ++mf) {
                    int m = mf * 16 + col;
                    float v0 = acc[nf][mf][0] + b4[0]; v0 = v0 > 0.f ? v0 : 0.f;
                    float v1 = acc[nf][mf][1] + b4[1]; v1 = v1 > 0.f ? v1 : 0.f;
                    float v2 = acc[nf][mf][2] + b4[2]; v2 = v2 > 0.f ? v2 : 0.f;
                    float v3 = acc[nf][mf][3] + b4[3]; v3 = v3 > 0.f ? v3 : 0.f;
                    u32x2 w;
                    w[0] = pack_bf2(v0, v1);
                    w[1] = pack_bf2(v2, v3);
                    int byte = (m * 512 + n0 * 2) ^ ((m & 7) << 4);
                    *(u32x2*)((char*)h_lds + byte) = w;
                }
            }
            __syncthreads();
        }

        // ---- layer 2: unswapped MFMA + pair-sum reduction ----
        {
            const unsigned short* Wl = Wt + (size_t)2 * HID * HID
                                          + (size_t)(wid * 64) * HID;
            f32x4 acc[4][4];   // [mf][nf]
            #pragma unroll
            for (int mf = 0; mf < 4; ++mf)
                #pragma unroll
                for (int nf = 0; nf < 4; ++nf)
                    acc[mf][nf] = (f32x4){0.f, 0.f, 0.f, 0.f};

            #pragma unroll 2
            for (int ks = 0; ks < 8; ++ks) {
                int ko = ks * 32 + rg * 8;
                s16x8 wfr[4];
                #pragma unroll
                for (int nf = 0; nf < 4; ++nf)
                    wfr[nf] = *(const s16x8*)(Wl + (nf * 16 + col) * HID + ko);
                s16x8 hfr[4];
                #pragma unroll
                for (int mf = 0; mf < 4; ++mf) {
                    int m = mf * 16 + col;
                    int byte = (m * 512 + ko * 2) ^ ((m & 7) << 4);
                    hfr[mf] = *(const s16x8*)((const char*)h_lds + byte);
                }
                #pragma unroll
                for (int mf = 0; mf < 4; ++mf)
                    #pragma unroll
                    for (int nf = 0; nf < 4; ++nf)
                        acc[mf][nf] = __builtin_amdgcn_mfma_f32_16x16x32_bf16(
                            hfr[mf], wfr[nf], acc[mf][nf], 0, 0, 0);
            }

            // relu + sum over the 64 pairs: in-lane over (mf, r), then rg groups
            #pragma unroll
            for (int nf = 0; nf < 4; ++nf) {
                float bv = g4_b[wid * 64 + nf * 16 + col];
                float s = 0.f;
                #pragma unroll
                for (int mf = 0; mf < 4; ++mf)
                    #pragma unroll
                    for (int r = 0; r < 4; ++r) {
                        float v = acc[mf][nf][r] + bv;
                        s += v > 0.f ? v : 0.f;
                    }
                s += __shfl_xor(s, 16);
                s += __shfl_xor(s, 32);
                pacc[nf] += s;
            }
            __syncthreads();   // h fully read before next pp's staging
        }
    }

    if (rg == 0) {
        #pragma unroll
        for (int nf = 0; nf < 4; ++nf)
            partial[(size_t)(b * NTILE + t) * HID + wid * 64 + nf * 16 + col]
                = pacc[nf];
    }
}

// ---------------------------------------------------------------------------
// Kernel 4: per-batch reduce over tiles + f-network (fp32) + log_softmax
// ---------------------------------------------------------------------------
__global__ __launch_bounds__(256) void fuse_kernel(
        const float* __restrict__ partial,
        const float* __restrict__ f1_w, const float* __restrict__ f1_b,
        const float* __restrict__ f2_w, const float* __restrict__ f2_b,
        const float* __restrict__ f3_w, const float* __restrict__ f3_b,
        float* __restrict__ out) {
    int b = blockIdx.x;
    int tid = threadIdx.x;
    __shared__ float xg[HID];
    __shared__ float h1[HID];
    __shared__ float h2[HID];
    __shared__ float lred[NOUT];
    __shared__ float lse;

    float s = 0.f;
    for (int t = 0; t < NTILE; ++t)
        s += partial[(size_t)(b * NTILE + t) * HID + tid];
    xg[tid] = s;
    __syncthreads();

    float a1 = f1_b[tid];
    for (int k = 0; k < HID; ++k)
        a1 += xg[k] * f1_w[k * HID + tid];
    h1[tid] = a1 > 0.f ? a1 : 0.f;
    __syncthreads();

    float a2 = f2_b[tid];
    for (int k = 0; k < HID; ++k)
        a2 += h1[k] * f2_w[k * HID + tid];
    h2[tid] = a2 > 0.f ? a2 : 0.f;
    __syncthreads();

    float logit = 0.f;
    if (tid < NOUT) {
        logit = f3_b[tid];
        for (int k = 0; k < HID; ++k)
            logit += h2[k] * f3_w[k * NOUT + tid];
        lred[tid] = logit;
    }
    __syncthreads();
    if (tid == 0) {
        float mx = lred[0];
        for (int j = 1; j < NOUT; ++j) mx = fmaxf(mx, lred[j]);
        float se = 0.f;
        for (int j = 0; j < NOUT; ++j) se += expf(lred[j] - mx);
        lse = mx + logf(se);
    }
    __syncthreads();
    if (tid < NOUT)
        out[b * NOUT + tid] = logit - lse;
}

// ---------------------------------------------------------------------------
extern "C" void kernel_launch(void* const* d_in, const int* in_sizes, int n_in,
                              void* d_out, int out_size, void* d_ws, size_t ws_size,
                              hipStream_t stream) {
    const float* x    = (const float*)d_in[0];
    const float* qst  = (const float*)d_in[1];
    const float* g1_w = (const float*)d_in[2];
    const float* g1_b = (const float*)d_in[3];
    const float* g2_w = (const float*)d_in[4];
    const float* g2_b = (const float*)d_in[5];
    const float* g3_w = (const float*)d_in[6];
    const float* g3_b = (const float*)d_in[7];
    const float* g4_w = (const float*)d_in[8];
    const float* g4_b = (const float*)d_in[9];
    const float* f1_w = (const float*)d_in[10];
    const float* f1_b = (const float*)d_in[11];
    const float* f2_w = (const float*)d_in[12];
    const float* f2_b = (const float*)d_in[13];
    const float* f3_w = (const float*)d_in[14];
    const float* f3_b = (const float*)d_in[15];
    float* out = (float*)d_out;

    char* ws = (char*)d_ws;
    unsigned short* Abf = (unsigned short*)ws;                          // 2 MiB
    unsigned short* Bbf = (unsigned short*)(ws + (2u << 20));           // 2 MiB
    unsigned short* Wt  = (unsigned short*)(ws + (4u << 20));           // 384 KiB
    float* partial      = (float*)(ws + (4u << 20) + (512u << 10));     // 2 MiB

    prep_kernel<<<NB, 256, 0, stream>>>(x, qst, g1_w, g1_b, Abf, Bbf);
    wconv_kernel<<<3 * 256, 256, 0, stream>>>(g2_w, g3_w, g4_w, Wt);
    rn_main<<<NB * NTILE, 256, 0, stream>>>(Abf, Bbf, Wt, g2_b, g3_b, g4_b, partial);
    fuse_kernel<<<NB, 256, 0, stream>>>(partial, f1_w, f1_b, f2_w, f2_b, f3_w, f3_b, out);
}

// Round 5
// 298.367 us; speedup vs baseline: 1.0451x; 1.0451x over previous
//
#include <hip/hip_runtime.h>
#include <hip/hip_bf16.h>
#include <math.h>

#define NB   64      // batch
#define D2   64      // objects per batch
#define OBJ  26      // K+2 features per object
#define NQST 11
#define HID  256
#define NOUT 28
#define NTILE 32     // p-tiles per batch (2 p's each, processed sequentially)

typedef __attribute__((ext_vector_type(8))) short s16x8;
typedef __attribute__((ext_vector_type(4))) float f32x4;
typedef __attribute__((ext_vector_type(2))) unsigned int u32x2;

__device__ __forceinline__ unsigned short f2bf(float f) {
    union { float f; unsigned u; } v; v.f = f;
    unsigned r = v.u + 0x7FFFu + ((v.u >> 16) & 1u);
    return (unsigned short)(r >> 16);
}
__device__ __forceinline__ float bf2f(unsigned short h) {
    union { unsigned u; float f; } v; v.u = ((unsigned)h) << 16;
    return v.f;
}
__device__ __forceinline__ unsigned pack_bf2(float a, float b) {
    return ((unsigned)f2bf(a)) | (((unsigned)f2bf(b)) << 16);
}

// ---------------------------------------------------------------------------
// Kernel 1: per-batch A[q][n], B[p][n] (bf16) from the g1 decomposition.
//   A[q] = o[q] @ g1_w[0:26]
//   B[p] = o[p] @ g1_w[26:52] + qst @ g1_w[52:63] + g1_b
// ---------------------------------------------------------------------------
__global__ __launch_bounds__(256) void prep_kernel(
        const float* __restrict__ x, const float* __restrict__ qst,
        const float* __restrict__ g1_w, const float* __restrict__ g1_b,
        unsigned short* __restrict__ Abf, unsigned short* __restrict__ Bbf) {
    int b = blockIdx.x;
    int tid = threadIdx.x;
    __shared__ float o_lds[D2][OBJ];
    for (int idx = tid; idx < 24 * D2; idx += 256) {
        int c = idx >> 6, pos = idx & 63;
        o_lds[pos][c] = x[(b * 24 + c) * D2 + pos];
    }
    if (tid < D2) {
        o_lds[tid][24] = (float)(tid & 7) * (8.0f / 7.0f) - 4.0f;  // cx = coords[col]
        o_lds[tid][25] = (float)(tid >> 3) * (8.0f / 7.0f) - 4.0f; // cy = coords[row]
    }
    __syncthreads();
    int n = tid;  // 0..255
    float qpart = g1_b[n];
    for (int s = 0; s < NQST; ++s)
        qpart += qst[b * NQST + s] * g1_w[(2 * OBJ + s) * HID + n];
    for (int q0 = 0; q0 < D2; q0 += 16) {
        float accA[16], accB[16];
        #pragma unroll
        for (int i = 0; i < 16; ++i) { accA[i] = 0.f; accB[i] = 0.f; }
        for (int c = 0; c < OBJ; ++c) {
            float wA = g1_w[c * HID + n];
            float wB = g1_w[(OBJ + c) * HID + n];
            #pragma unroll
            for (int i = 0; i < 16; ++i) {
                float ov = o_lds[q0 + i][c];
                accA[i] += ov * wA;
                accB[i] += ov * wB;
            }
        }
        #pragma unroll
        for (int i = 0; i < 16; ++i) {
            int q = q0 + i;
            Abf[(b * D2 + q) * HID + n] = f2bf(accA[i]);
            Bbf[(b * D2 + q) * HID + n] = f2bf(accB[i] + qpart);
        }
    }
}

// ---------------------------------------------------------------------------
// Kernel 2: convert+transpose g2/g3/g4 weights: Wt[l][n][k] = W_l[k][n] (bf16)
// ---------------------------------------------------------------------------
__global__ __launch_bounds__(256) void wconv_kernel(
        const float* __restrict__ g2_w, const float* __restrict__ g3_w,
        const float* __restrict__ g4_w, unsigned short* __restrict__ Wt) {
    int l = blockIdx.x >> 8;
    int n = blockIdx.x & 255;
    const float* W = (l == 0) ? g2_w : ((l == 1) ? g3_w : g4_w);
    int k = threadIdx.x;
    Wt[(l * HID + n) * HID + k] = f2bf(W[k * HID + n]);
}

// ---------------------------------------------------------------------------
// Kernel 3: main fused g-network.
// 256 threads = 4 waves; per WG: batch b, tile t, 2 p's sequential, M=64 tile.
// Each wave owns a 64-col n-slice: acc[4][4] = 64 regs (AGPR side of the
// unified file); with unroll-2 two frag sets in flight = +64; live ~150.
// __launch_bounds__(256, 3): combined reg cap = 512/3 = 170 (fits; at
// (256,4)=128 this SPILLED -> 230 MB scratch traffic in round 4).
// 3 blocks/CU (32 KiB LDS each) = 3 independent barrier domains.
// Layers 0,1 use SWAPPED operands mfma(W,h) -> D[n][m]: per-lane 4 consecutive
// n at fixed m -> packed ds_write_b64 epilogue (16 writes vs 32 b16).
// Layer 2 unswapped -> in-lane pair-sum + 2 shuffles.
// ---------------------------------------------------------------------------
__global__ __launch_bounds__(256, 3) void rn_main(
        const unsigned short* __restrict__ Abf, const unsigned short* __restrict__ Bbf,
        const unsigned short* __restrict__ Wt,
        const float* __restrict__ g2_b, const float* __restrict__ g3_b,
        const float* __restrict__ g4_b, float* __restrict__ partial) {
    // XCD-aware swizzle: 2048 WGs, 8 XCDs (2048 % 8 == 0 -> bijective)
    int wg = blockIdx.x;
    int swz = (wg & 7) * 256 + (wg >> 3);
    int b = swz >> 5;
    int t = swz & 31;

    __shared__ unsigned short h_lds[D2 * HID];   // 32 KiB

    int tid = threadIdx.x;   // 0..255
    int lane = tid & 63;
    int wid = tid >> 6;      // wave 0..3 -> n-slice of 64
    int rg = lane >> 4;      // 0..3
    int col = lane & 15;

    const unsigned short* Ab = Abf + (size_t)(b * D2) * HID;

    float pacc[4] = {0.f, 0.f, 0.f, 0.f};

    for (int pp = 0; pp < 2; ++pp) {
        const unsigned short* Bb = Bbf + (size_t)(b * D2 + t * 2 + pp) * HID;

        // ---- layer 1 staging: h[m][k] = relu(A[q=m][k] + B[p][k]) ----
        #pragma unroll
        for (int i = 0; i < 8; ++i) {
            int c = tid + i * 256;       // 2048 chunks of 8 bf16
            int m = c >> 5;              // 0..63
            int k0 = (c & 31) * 8;
            s16x8 av = *(const s16x8*)(Ab + m * HID + k0);
            s16x8 bv = *(const s16x8*)(Bb + k0);
            s16x8 hv;
            #pragma unroll
            for (int j = 0; j < 8; ++j) {
                float f = bf2f((unsigned short)av[j]) + bf2f((unsigned short)bv[j]);
                f = f > 0.f ? f : 0.f;
                hv[j] = (short)f2bf(f);
            }
            int byte = (m * 512 + k0 * 2) ^ ((m & 7) << 4);
            *(s16x8*)((char*)h_lds + byte) = hv;
        }
        __syncthreads();

        // ---- layers 0,1: swapped-operand MFMA, packed in-place writeback ----
        for (int layer = 0; layer < 2; ++layer) {
            const unsigned short* Wl = Wt + (size_t)layer * HID * HID
                                          + (size_t)(wid * 64) * HID;
            const float* bias = (layer == 0) ? g2_b : g3_b;

            f32x4 acc[4][4];   // [nf][mf]
            #pragma unroll
            for (int nf = 0; nf < 4; ++nf)
                #pragma unroll
                for (int mf = 0; mf < 4; ++mf)
                    acc[nf][mf] = (f32x4){0.f, 0.f, 0.f, 0.f};

            #pragma unroll 2
            for (int ks = 0; ks < 8; ++ks) {
                int ko = ks * 32 + rg * 8;   // k element base for this lane
                s16x8 wfr[4];
                #pragma unroll
                for (int nf = 0; nf < 4; ++nf)
                    wfr[nf] = *(const s16x8*)(Wl + (nf * 16 + col) * HID + ko);
                s16x8 hfr[4];
                #pragma unroll
                for (int mf = 0; mf < 4; ++mf) {
                    int m = mf * 16 + col;
                    int byte = (m * 512 + ko * 2) ^ ((m & 7) << 4);
                    hfr[mf] = *(const s16x8*)((const char*)h_lds + byte);
                }
                #pragma unroll
                for (int nf = 0; nf < 4; ++nf)
                    #pragma unroll
                    for (int mf = 0; mf < 4; ++mf)
                        acc[nf][mf] = __builtin_amdgcn_mfma_f32_16x16x32_bf16(
                            wfr[nf], hfr[mf], acc[nf][mf], 0, 0, 0);
            }
            __syncthreads();   // every wave has read all of h

            // epilogue: D[n][m]: n = wid*64+nf*16+rg*4+r, m = mf*16+col
            #pragma unroll
            for (int nf = 0; nf < 4; ++nf) {
                int n0 = wid * 64 + nf * 16 + rg * 4;
                f32x4 b4 = *(const f32x4*)(bias + n0);
                #pragma unroll
                for (int mf = 0; mf < 4; ++mf) {
                    int m = mf * 16 + col;
                    float v0 = acc[nf][mf][0] + b4[0]; v0 = v0 > 0.f ? v0 : 0.f;
                    float v1 = acc[nf][mf][1] + b4[1]; v1 = v1 > 0.f ? v1 : 0.f;
                    float v2 = acc[nf][mf][2] + b4[2]; v2 = v2 > 0.f ? v2 : 0.f;
                    float v3 = acc[nf][mf][3] + b4[3]; v3 = v3 > 0.f ? v3 : 0.f;
                    u32x2 w;
                    w[0] = pack_bf2(v0, v1);
                    w[1] = pack_bf2(v2, v3);
                    int byte = (m * 512 + n0 * 2) ^ ((m & 7) << 4);
                    *(u32x2*)((char*)h_lds + byte) = w;
                }
            }
            __syncthreads();
        }

        // ---- layer 2: unswapped MFMA + pair-sum reduction ----
        {
            const unsigned short* Wl = Wt + (size_t)2 * HID * HID
                                          + (size_t)(wid * 64) * HID;
            f32x4 acc[4][4];   // [mf][nf]
            #pragma unroll
            for (int mf = 0; mf < 4; ++mf)
                #pragma unroll
                for (int nf = 0; nf < 4; ++nf)
                    acc[mf][nf] = (f32x4){0.f, 0.f, 0.f, 0.f};

            #pragma unroll 2
            for (int ks = 0; ks < 8; ++ks) {
                int ko = ks * 32 + rg * 8;
                s16x8 wfr[4];
                #pragma unroll
                for (int nf = 0; nf < 4; ++nf)
                    wfr[nf] = *(const s16x8*)(Wl + (nf * 16 + col) * HID + ko);
                s16x8 hfr[4];
                #pragma unroll
                for (int mf = 0; mf < 4; ++mf) {
                    int m = mf * 16 + col;
                    int byte = (m * 512 + ko * 2) ^ ((m & 7) << 4);
                    hfr[mf] = *(const s16x8*)((const char*)h_lds + byte);
                }
                #pragma unroll
                for (int mf = 0; mf < 4; ++mf)
                    #pragma unroll
                    for (int nf = 0; nf < 4; ++nf)
                        acc[mf][nf] = __builtin_amdgcn_mfma_f32_16x16x32_bf16(
                            hfr[mf], wfr[nf], acc[mf][nf], 0, 0, 0);
            }

            // relu + sum over the 64 pairs: in-lane over (mf, r), then rg groups
            #pragma unroll
            for (int nf = 0; nf < 4; ++nf) {
                float bv = g4_b[wid * 64 + nf * 16 + col];
                float s = 0.f;
                #pragma unroll
                for (int mf = 0; mf < 4; ++mf)
                    #pragma unroll
                    for (int r = 0; r < 4; ++r) {
                        float v = acc[mf][nf][r] + bv;
                        s += v > 0.f ? v : 0.f;
                    }
                s += __shfl_xor(s, 16);
                s += __shfl_xor(s, 32);
                pacc[nf] += s;
            }
            __syncthreads();   // h fully read before next pp's staging
        }
    }

    if (rg == 0) {
        #pragma unroll
        for (int nf = 0; nf < 4; ++nf)
            partial[(size_t)(b * NTILE + t) * HID + wid * 64 + nf * 16 + col]
                = pacc[nf];
    }
}

// ---------------------------------------------------------------------------
// Kernel 4: per-batch reduce over tiles + f-network (fp32) + log_softmax
// ---------------------------------------------------------------------------
__global__ __launch_bounds__(256) void fuse_kernel(
        const float* __restrict__ partial,
        const float* __restrict__ f1_w, const float* __restrict__ f1_b,
        const float* __restrict__ f2_w, const float* __restrict__ f2_b,
        const float* __restrict__ f3_w, const float* __restrict__ f3_b,
        float* __restrict__ out) {
    int b = blockIdx.x;
    int tid = threadIdx.x;
    __shared__ float xg[HID];
    __shared__ float h1[HID];
    __shared__ float h2[HID];
    __shared__ float lred[NOUT];
    __shared__ float lse;

    float s = 0.f;
    for (int t = 0; t < NTILE; ++t)
        s += partial[(size_t)(b * NTILE + t) * HID + tid];
    xg[tid] = s;
    __syncthreads();

    float a1 = f1_b[tid];
    for (int k = 0; k < HID; ++k)
        a1 += xg[k] * f1_w[k * HID + tid];
    h1[tid] = a1 > 0.f ? a1 : 0.f;
    __syncthreads();

    float a2 = f2_b[tid];
    for (int k = 0; k < HID; ++k)
        a2 += h1[k] * f2_w[k * HID + tid];
    h2[tid] = a2 > 0.f ? a2 : 0.f;
    __syncthreads();

    float logit = 0.f;
    if (tid < NOUT) {
        logit = f3_b[tid];
        for (int k = 0; k < HID; ++k)
            logit += h2[k] * f3_w[k * NOUT + tid];
        lred[tid] = logit;
    }
    __syncthreads();
    if (tid == 0) {
        float mx = lred[0];
        for (int j = 1; j < NOUT; ++j) mx = fmaxf(mx, lred[j]);
        float se = 0.f;
        for (int j = 0; j < NOUT; ++j) se += expf(lred[j] - mx);
        lse = mx + logf(se);
    }
    __syncthreads();
    if (tid < NOUT)
        out[b * NOUT + tid] = logit - lse;
}

// ---------------------------------------------------------------------------
extern "C" void kernel_launch(void* const* d_in, const int* in_sizes, int n_in,
                              void* d_out, int out_size, void* d_ws, size_t ws_size,
                              hipStream_t stream) {
    const float* x    = (const float*)d_in[0];
    const float* qst  = (const float*)d_in[1];
    const float* g1_w = (const float*)d_in[2];
    const float* g1_b = (const float*)d_in[3];
    const float* g2_w = (const float*)d_in[4];
    const float* g2_b = (const float*)d_in[5];
    const float* g3_w = (const float*)d_in[6];
    const float* g3_b = (const float*)d_in[7];
    const float* g4_w = (const float*)d_in[8];
    const float* g4_b = (const float*)d_in[9];
    const float* f1_w = (const float*)d_in[10];
    const float* f1_b = (const float*)d_in[11];
    const float* f2_w = (const float*)d_in[12];
    const float* f2_b = (const float*)d_in[13];
    const float* f3_w = (const float*)d_in[14];
    const float* f3_b = (const float*)d_in[15];
    float* out = (float*)d_out;

    char* ws = (char*)d_ws;
    unsigned short* Abf = (unsigned short*)ws;                          // 2 MiB
    unsigned short* Bbf = (unsigned short*)(ws + (2u << 20));           // 2 MiB
    unsigned short* Wt  = (unsigned short*)(ws + (4u << 20));           // 384 KiB
    float* partial      = (float*)(ws + (4u << 20) + (512u << 10));     // 2 MiB

    prep_kernel<<<NB, 256, 0, stream>>>(x, qst, g1_w, g1_b, Abf, Bbf);
    wconv_kernel<<<3 * 256, 256, 0, stream>>>(g2_w, g3_w, g4_w, Wt);
    rn_main<<<NB * NTILE, 256, 0, stream>>>(Abf, Bbf, Wt, g2_b, g3_b, g4_b, partial);
    fuse_kernel<<<NB, 256, 0, stream>>>(partial, f1_w, f1_b, f2_w, f2_b, f3_w, f3_b, out);
}

// Round 6
// 226.209 us; speedup vs baseline: 1.3784x; 1.3190x over previous
//
#include <hip/hip_runtime.h>
#include <hip/hip_bf16.h>
#include <math.h>

#define NB   64      // batch
#define D2   64      // objects per batch
#define OBJ  26      // K+2 features per object
#define NQST 11
#define HID  256
#define NOUT 28
#define NTILE 32     // p-tiles per batch (2 p's each, processed sequentially)

typedef __attribute__((ext_vector_type(8))) short s16x8;
typedef __attribute__((ext_vector_type(4))) float f32x4;
typedef __attribute__((ext_vector_type(2))) unsigned int u32x2;

__device__ __forceinline__ unsigned short f2bf(float f) {
    union { float f; unsigned u; } v; v.f = f;
    unsigned r = v.u + 0x7FFFu + ((v.u >> 16) & 1u);
    return (unsigned short)(r >> 16);
}
__device__ __forceinline__ float bf2f(unsigned short h) {
    union { unsigned u; float f; } v; v.u = ((unsigned)h) << 16;
    return v.f;
}
__device__ __forceinline__ unsigned pack_bf2(float a, float b) {
    return ((unsigned)f2bf(a)) | (((unsigned)f2bf(b)) << 16);
}

// ---------------------------------------------------------------------------
// Kernel 1: per-batch A[q][n], B[p][n] (bf16) from the g1 decomposition.
//   A[q] = o[q] @ g1_w[0:26]
//   B[p] = o[p] @ g1_w[26:52] + qst @ g1_w[52:63] + g1_b
// ---------------------------------------------------------------------------
__global__ __launch_bounds__(256) void prep_kernel(
        const float* __restrict__ x, const float* __restrict__ qst,
        const float* __restrict__ g1_w, const float* __restrict__ g1_b,
        unsigned short* __restrict__ Abf, unsigned short* __restrict__ Bbf) {
    int b = blockIdx.x;
    int tid = threadIdx.x;
    __shared__ float o_lds[D2][OBJ];
    for (int idx = tid; idx < 24 * D2; idx += 256) {
        int c = idx >> 6, pos = idx & 63;
        o_lds[pos][c] = x[(b * 24 + c) * D2 + pos];
    }
    if (tid < D2) {
        o_lds[tid][24] = (float)(tid & 7) * (8.0f / 7.0f) - 4.0f;  // cx = coords[col]
        o_lds[tid][25] = (float)(tid >> 3) * (8.0f / 7.0f) - 4.0f; // cy = coords[row]
    }
    __syncthreads();
    int n = tid;  // 0..255
    float qpart = g1_b[n];
    for (int s = 0; s < NQST; ++s)
        qpart += qst[b * NQST + s] * g1_w[(2 * OBJ + s) * HID + n];
    for (int q0 = 0; q0 < D2; q0 += 16) {
        float accA[16], accB[16];
        #pragma unroll
        for (int i = 0; i < 16; ++i) { accA[i] = 0.f; accB[i] = 0.f; }
        for (int c = 0; c < OBJ; ++c) {
            float wA = g1_w[c * HID + n];
            float wB = g1_w[(OBJ + c) * HID + n];
            #pragma unroll
            for (int i = 0; i < 16; ++i) {
                float ov = o_lds[q0 + i][c];
                accA[i] += ov * wA;
                accB[i] += ov * wB;
            }
        }
        #pragma unroll
        for (int i = 0; i < 16; ++i) {
            int q = q0 + i;
            Abf[(b * D2 + q) * HID + n] = f2bf(accA[i]);
            Bbf[(b * D2 + q) * HID + n] = f2bf(accB[i] + qpart);
        }
    }
}

// ---------------------------------------------------------------------------
// Kernel 2: convert+transpose g2/g3/g4 weights: Wt[l][n][k] = W_l[k][n] (bf16)
// ---------------------------------------------------------------------------
__global__ __launch_bounds__(256) void wconv_kernel(
        const float* __restrict__ g2_w, const float* __restrict__ g3_w,
        const float* __restrict__ g4_w, unsigned short* __restrict__ Wt) {
    int l = blockIdx.x >> 8;
    int n = blockIdx.x & 255;
    const float* W = (l == 0) ? g2_w : ((l == 1) ? g3_w : g4_w);
    int k = threadIdx.x;
    Wt[(l * HID + n) * HID + k] = f2bf(W[k * HID + n]);
}

// ---------------------------------------------------------------------------
// Kernel 3: main fused g-network.
// 256 threads = 4 waves; per WG: batch b, tile t, 2 p's sequential, M=64 tile.
// Each wave owns a 64-col n-slice: acc[4][4] = 64 regs.
// REGISTER CAP HISTORY: (256,4)=128 cap -> spilled (230 MB scratch, r4);
// (256,3)=~168 cap -> STILL spilled (143 MB, r5) because unroll-2 pipelining
// keeps 2 frag sets + prefetched W loads + staging batch live (~190 peak).
// Now (256,2) = 256 cap: ~50 regs slack for the scheduler. 2 blocks/CU.
// Layers 0,1 use SWAPPED operands mfma(W,h) -> D[n][m]: per-lane 4 consecutive
// n at fixed m -> packed ds_write_b64 epilogue. Layer 2 unswapped -> in-lane
// pair-sum + 2 shuffles.
// ---------------------------------------------------------------------------
__global__ __launch_bounds__(256, 2) void rn_main(
        const unsigned short* __restrict__ Abf, const unsigned short* __restrict__ Bbf,
        const unsigned short* __restrict__ Wt,
        const float* __restrict__ g2_b, const float* __restrict__ g3_b,
        const float* __restrict__ g4_b, float* __restrict__ partial) {
    // XCD-aware swizzle: 2048 WGs, 8 XCDs (2048 % 8 == 0 -> bijective)
    int wg = blockIdx.x;
    int swz = (wg & 7) * 256 + (wg >> 3);
    int b = swz >> 5;
    int t = swz & 31;

    __shared__ unsigned short h_lds[D2 * HID];   // 32 KiB

    int tid = threadIdx.x;   // 0..255
    int lane = tid & 63;
    int wid = tid >> 6;      // wave 0..3 -> n-slice of 64
    int rg = lane >> 4;      // 0..3
    int col = lane & 15;

    const unsigned short* Ab = Abf + (size_t)(b * D2) * HID;

    float pacc[4] = {0.f, 0.f, 0.f, 0.f};

    for (int pp = 0; pp < 2; ++pp) {
        const unsigned short* Bb = Bbf + (size_t)(b * D2 + t * 2 + pp) * HID;

        // ---- layer 1 staging: h[m][k] = relu(A[q=m][k] + B[p][k]) ----
        // two unroll-4 batches: 8 loads (32 regs) in flight, not 16 (64)
        for (int half = 0; half < 2; ++half) {
            #pragma unroll
            for (int i = 0; i < 4; ++i) {
                int c = tid + (half * 4 + i) * 256;  // 2048 chunks of 8 bf16
                int m = c >> 5;              // 0..63
                int k0 = (c & 31) * 8;
                s16x8 av = *(const s16x8*)(Ab + m * HID + k0);
                s16x8 bv = *(const s16x8*)(Bb + k0);
                s16x8 hv;
                #pragma unroll
                for (int j = 0; j < 8; ++j) {
                    float f = bf2f((unsigned short)av[j]) + bf2f((unsigned short)bv[j]);
                    f = f > 0.f ? f : 0.f;
                    hv[j] = (short)f2bf(f);
                }
                int byte = (m * 512 + k0 * 2) ^ ((m & 7) << 4);
                *(s16x8*)((char*)h_lds + byte) = hv;
            }
        }
        __syncthreads();

        // ---- layers 0,1: swapped-operand MFMA, packed in-place writeback ----
        for (int layer = 0; layer < 2; ++layer) {
            const unsigned short* Wl = Wt + (size_t)layer * HID * HID
                                          + (size_t)(wid * 64) * HID;
            const float* bias = (layer == 0) ? g2_b : g3_b;

            f32x4 acc[4][4];   // [nf][mf]
            #pragma unroll
            for (int nf = 0; nf < 4; ++nf)
                #pragma unroll
                for (int mf = 0; mf < 4; ++mf)
                    acc[nf][mf] = (f32x4){0.f, 0.f, 0.f, 0.f};

            #pragma unroll 2
            for (int ks = 0; ks < 8; ++ks) {
                int ko = ks * 32 + rg * 8;   // k element base for this lane
                s16x8 wfr[4];
                #pragma unroll
                for (int nf = 0; nf < 4; ++nf)
                    wfr[nf] = *(const s16x8*)(Wl + (nf * 16 + col) * HID + ko);
                s16x8 hfr[4];
                #pragma unroll
                for (int mf = 0; mf < 4; ++mf) {
                    int m = mf * 16 + col;
                    int byte = (m * 512 + ko * 2) ^ ((m & 7) << 4);
                    hfr[mf] = *(const s16x8*)((const char*)h_lds + byte);
                }
                #pragma unroll
                for (int nf = 0; nf < 4; ++nf)
                    #pragma unroll
                    for (int mf = 0; mf < 4; ++mf)
                        acc[nf][mf] = __builtin_amdgcn_mfma_f32_16x16x32_bf16(
                            wfr[nf], hfr[mf], acc[nf][mf], 0, 0, 0);
            }
            __syncthreads();   // every wave has read all of h

            // epilogue: D[n][m]: n = wid*64+nf*16+rg*4+r, m = mf*16+col
            #pragma unroll
            for (int nf = 0; nf < 4; ++nf) {
                int n0 = wid * 64 + nf * 16 + rg * 4;
                f32x4 b4 = *(const f32x4*)(bias + n0);
                #pragma unroll
                for (int mf = 0; mf < 4; ++mf) {
                    int m = mf * 16 + col;
                    float v0 = acc[nf][mf][0] + b4[0]; v0 = v0 > 0.f ? v0 : 0.f;
                    float v1 = acc[nf][mf][1] + b4[1]; v1 = v1 > 0.f ? v1 : 0.f;
                    float v2 = acc[nf][mf][2] + b4[2]; v2 = v2 > 0.f ? v2 : 0.f;
                    float v3 = acc[nf][mf][3] + b4[3]; v3 = v3 > 0.f ? v3 : 0.f;
                    u32x2 w;
                    w[0] = pack_bf2(v0, v1);
                    w[1] = pack_bf2(v2, v3);
                    int byte = (m * 512 + n0 * 2) ^ ((m & 7) << 4);
                    *(u32x2*)((char*)h_lds + byte) = w;
                }
            }
            __syncthreads();
        }

        // ---- layer 2: unswapped MFMA + pair-sum reduction ----
        {
            const unsigned short* Wl = Wt + (size_t)2 * HID * HID
                                          + (size_t)(wid * 64) * HID;
            f32x4 acc[4][4];   // [mf][nf]
            #pragma unroll
            for (int mf = 0; mf < 4; ++mf)
                #pragma unroll
                for (int nf = 0; nf < 4; ++nf)
                    acc[mf][nf] = (f32x4){0.f, 0.f, 0.f, 0.f};

            #pragma unroll 2
            for (int ks = 0; ks < 8; ++ks) {
                int ko = ks * 32 + rg * 8;
                s16x8 wfr[4];
                #pragma unroll
                for (int nf = 0; nf < 4; ++nf)
                    wfr[nf] = *(const s16x8*)(Wl + (nf * 16 + col) * HID + ko);
                s16x8 hfr[4];
                #pragma unroll
                for (int mf = 0; mf < 4; ++mf) {
                    int m = mf * 16 + col;
                    int byte = (m * 512 + ko * 2) ^ ((m & 7) << 4);
                    hfr[mf] = *(const s16x8*)((const char*)h_lds + byte);
                }
                #pragma unroll
                for (int mf = 0; mf < 4; ++mf)
                    #pragma unroll
                    for (int nf = 0; nf < 4; ++nf)
                        acc[mf][nf] = __builtin_amdgcn_mfma_f32_16x16x32_bf16(
                            hfr[mf], wfr[nf], acc[mf][nf], 0, 0, 0);
            }

            // relu + sum over the 64 pairs: in-lane over (mf, r), then rg groups
            #pragma unroll
            for (int nf = 0; nf < 4; ++nf) {
                float bv = g4_b[wid * 64 + nf * 16 + col];
                float s = 0.f;
                #pragma unroll
                for (int mf = 0; mf < 4; ++mf)
                    #pragma unroll
                    for (int r = 0; r < 4; ++r) {
                        float v = acc[mf][nf][r] + bv;
                        s += v > 0.f ? v : 0.f;
                    }
                s += __shfl_xor(s, 16);
                s += __shfl_xor(s, 32);
                pacc[nf] += s;
            }
            __syncthreads();   // h fully read before next pp's staging
        }
    }

    if (rg == 0) {
        #pragma unroll
        for (int nf = 0; nf < 4; ++nf)
            partial[(size_t)(b * NTILE + t) * HID + wid * 64 + nf * 16 + col]
                = pacc[nf];
    }
}

// ---------------------------------------------------------------------------
// Kernel 4: per-batch reduce over tiles + f-network (fp32) + log_softmax
// ---------------------------------------------------------------------------
__global__ __launch_bounds__(256) void fuse_kernel(
        const float* __restrict__ partial,
        const float* __restrict__ f1_w, const float* __restrict__ f1_b,
        const float* __restrict__ f2_w, const float* __restrict__ f2_b,
        const float* __restrict__ f3_w, const float* __restrict__ f3_b,
        float* __restrict__ out) {
    int b = blockIdx.x;
    int tid = threadIdx.x;
    __shared__ float xg[HID];
    __shared__ float h1[HID];
    __shared__ float h2[HID];
    __shared__ float lred[NOUT];
    __shared__ float lse;

    float s = 0.f;
    for (int t = 0; t < NTILE; ++t)
        s += partial[(size_t)(b * NTILE + t) * HID + tid];
    xg[tid] = s;
    __syncthreads();

    float a1 = f1_b[tid];
    for (int k = 0; k < HID; ++k)
        a1 += xg[k] * f1_w[k * HID + tid];
    h1[tid] = a1 > 0.f ? a1 : 0.f;
    __syncthreads();

    float a2 = f2_b[tid];
    for (int k = 0; k < HID; ++k)
        a2 += h1[k] * f2_w[k * HID + tid];
    h2[tid] = a2 > 0.f ? a2 : 0.f;
    __syncthreads();

    float logit = 0.f;
    if (tid < NOUT) {
        logit = f3_b[tid];
        for (int k = 0; k < HID; ++k)
            logit += h2[k] * f3_w[k * NOUT + tid];
        lred[tid] = logit;
    }
    __syncthreads();
    if (tid == 0) {
        float mx = lred[0];
        for (int j = 1; j < NOUT; ++j) mx = fmaxf(mx, lred[j]);
        float se = 0.f;
        for (int j = 0; j < NOUT; ++j) se += expf(lred[j] - mx);
        lse = mx + logf(se);
    }
    __syncthreads();
    if (tid < NOUT)
        out[b * NOUT + tid] = logit - lse;
}

// ---------------------------------------------------------------------------
extern "C" void kernel_launch(void* const* d_in, const int* in_sizes, int n_in,
                              void* d_out, int out_size, void* d_ws, size_t ws_size,
                              hipStream_t stream) {
    const float* x    = (const float*)d_in[0];
    const float* qst  = (const float*)d_in[1];
    const float* g1_w = (const float*)d_in[2];
    const float* g1_b = (const float*)d_in[3];
    const float* g2_w = (const float*)d_in[4];
    const float* g2_b = (const float*)d_in[5];
    const float* g3_w = (const float*)d_in[6];
    const float* g3_b = (const float*)d_in[7];
    const float* g4_w = (const float*)d_in[8];
    const float* g4_b = (const float*)d_in[9];
    const float* f1_w = (const float*)d_in[10];
    const float* f1_b = (const float*)d_in[11];
    const float* f2_w = (const float*)d_in[12];
    const float* f2_b = (const float*)d_in[13];
    const float* f3_w = (const float*)d_in[14];
    const float* f3_b = (const float*)d_in[15];
    float* out = (float*)d_out;

    char* ws = (char*)d_ws;
    unsigned short* Abf = (unsigned short*)ws;                          // 2 MiB
    unsigned short* Bbf = (unsigned short*)(ws + (2u << 20));           // 2 MiB
    unsigned short* Wt  = (unsigned short*)(ws + (4u << 20));           // 384 KiB
    float* partial      = (float*)(ws + (4u << 20) + (512u << 10));     // 2 MiB

    prep_kernel<<<NB, 256, 0, stream>>>(x, qst, g1_w, g1_b, Abf, Bbf);
    wconv_kernel<<<3 * 256, 256, 0, stream>>>(g2_w, g3_w, g4_w, Wt);
    rn_main<<<NB * NTILE, 256, 0, stream>>>(Abf, Bbf, Wt, g2_b, g3_b, g4_b, partial);
    fuse_kernel<<<NB, 256, 0, stream>>>(partial, f1_w, f1_b, f2_w, f2_b, f3_w, f3_b, out);
}

// Round 7
// 220.018 us; speedup vs baseline: 1.4172x; 1.0281x over previous
//
#include <hip/hip_runtime.h>
#include <hip/hip_bf16.h>
#include <math.h>

#define NB   64      // batch
#define D2   64      // objects per batch
#define OBJ  26      // K+2 features per object
#define NQST 11
#define HID  256
#define NOUT 28
#define NTILE 32     // p-tiles per batch (2 p's each, processed sequentially)

typedef __attribute__((ext_vector_type(8))) short s16x8;
typedef __attribute__((ext_vector_type(4))) float f32x4;
typedef __attribute__((ext_vector_type(2))) unsigned int u32x2;

// native converts: compiler emits v_cvt_pk_bf16_f32 for paired uses
__device__ __forceinline__ unsigned short f2bf(float f) {
    __hip_bfloat16 h = __float2bfloat16(f);
    union { __hip_bfloat16 h; unsigned short u; } v; v.h = h; return v.u;
}
__device__ __forceinline__ float bf2f(unsigned short h) {
    union { unsigned u; float f; } v; v.u = ((unsigned)h) << 16;
    return v.f;
}
__device__ __forceinline__ unsigned pack_bf2(float a, float b) {
    return ((unsigned)f2bf(a)) | (((unsigned)f2bf(b)) << 16);
}

// ---------------------------------------------------------------------------
// Kernel 1 (merged): blocks 0..767 convert+transpose g2/g3/g4 weights;
// blocks 768..831 compute per-batch A/B from the g1 decomposition:
//   A[q] = o[q] @ g1_w[0:26]
//   B[p] = o[p] @ g1_w[26:52] + qst @ g1_w[52:63] + g1_b
// ---------------------------------------------------------------------------
__global__ __launch_bounds__(256) void prep_all(
        const float* __restrict__ x, const float* __restrict__ qst,
        const float* __restrict__ g1_w, const float* __restrict__ g1_b,
        const float* __restrict__ g2_w, const float* __restrict__ g3_w,
        const float* __restrict__ g4_w,
        unsigned short* __restrict__ Abf, unsigned short* __restrict__ Bbf,
        unsigned short* __restrict__ Wt) {
    if (blockIdx.x < 768) {
        int l = blockIdx.x >> 8;
        int n = blockIdx.x & 255;
        const float* W = (l == 0) ? g2_w : ((l == 1) ? g3_w : g4_w);
        int k = threadIdx.x;
        Wt[(l * HID + n) * HID + k] = f2bf(W[k * HID + n]);
        return;
    }
    int b = blockIdx.x - 768;
    int tid = threadIdx.x;
    __shared__ float o_lds[D2][OBJ];
    for (int idx = tid; idx < 24 * D2; idx += 256) {
        int c = idx >> 6, pos = idx & 63;
        o_lds[pos][c] = x[(b * 24 + c) * D2 + pos];
    }
    if (tid < D2) {
        o_lds[tid][24] = (float)(tid & 7) * (8.0f / 7.0f) - 4.0f;  // cx
        o_lds[tid][25] = (float)(tid >> 3) * (8.0f / 7.0f) - 4.0f; // cy
    }
    __syncthreads();
    int n = tid;  // 0..255
    float qpart = g1_b[n];
    for (int s = 0; s < NQST; ++s)
        qpart += qst[b * NQST + s] * g1_w[(2 * OBJ + s) * HID + n];
    for (int q0 = 0; q0 < D2; q0 += 16) {
        float accA[16], accB[16];
        #pragma unroll
        for (int i = 0; i < 16; ++i) { accA[i] = 0.f; accB[i] = 0.f; }
        for (int c = 0; c < OBJ; ++c) {
            float wA = g1_w[c * HID + n];
            float wB = g1_w[(OBJ + c) * HID + n];
            #pragma unroll
            for (int i = 0; i < 16; ++i) {
                float ov = o_lds[q0 + i][c];
                accA[i] += ov * wA;
                accB[i] += ov * wB;
            }
        }
        #pragma unroll
        for (int i = 0; i < 16; ++i) {
            int q = q0 + i;
            Abf[(b * D2 + q) * HID + n] = f2bf(accA[i]);
            Bbf[(b * D2 + q) * HID + n] = f2bf(accB[i] + qpart);
        }
    }
}

// ---------------------------------------------------------------------------
// rn_main helpers (all inlined)
// ---------------------------------------------------------------------------

// stage h[m][k] = relu(A[m][k] + B[k]) into hbuf (swizzled). A cached in areg.
template <bool LOADA>
__device__ __forceinline__ void stage_h(
        unsigned short* hbuf, const unsigned short* __restrict__ Bb,
        s16x8* areg, const unsigned short* __restrict__ Ab, int tid) {
    #pragma unroll
    for (int i = 0; i < 8; ++i) {
        int c = tid + i * 256;       // 2048 chunks of 8 bf16
        int m = c >> 5;              // 0..63
        int k0 = (c & 31) * 8;
        if (LOADA) areg[i] = *(const s16x8*)(Ab + m * HID + k0);
        s16x8 bv = *(const s16x8*)(Bb + k0);
        s16x8 hv;
        #pragma unroll
        for (int j = 0; j < 8; j += 2) {
            float f0 = bf2f((unsigned short)areg[i][j])     + bf2f((unsigned short)bv[j]);
            float f1 = bf2f((unsigned short)areg[i][j + 1]) + bf2f((unsigned short)bv[j + 1]);
            unsigned w = pack_bf2(fmaxf(f0, 0.f), fmaxf(f1, 0.f));
            hv[j]     = (short)(w & 0xFFFF);
            hv[j + 1] = (short)(w >> 16);
        }
        int byte = (m * 512 + k0 * 2) ^ ((m & 7) << 4);
        *(s16x8*)((char*)hbuf + byte) = hv;
    }
}

// layers 0/1: swapped-operand mfma(W,h) -> D[n][m]; bias preloaded into acc;
// epilogue relu+pack -> hout (different buffer than hin: no barrier needed
// between K-loop and epilogue).
__device__ __forceinline__ void layer_sw(
        const unsigned short* __restrict__ Wl, const float* __restrict__ bias,
        const unsigned short* hin, unsigned short* hout,
        int wid, int rg, int col) {
    const unsigned short* Ws = Wl + (size_t)(wid * 64) * HID;
    f32x4 acc[4][4];   // [nf][mf]
    #pragma unroll
    for (int nf = 0; nf < 4; ++nf) {
        f32x4 b4 = *(const f32x4*)(bias + wid * 64 + nf * 16 + rg * 4);
        #pragma unroll
        for (int mf = 0; mf < 4; ++mf)
            acc[nf][mf] = b4;               // bias-in-acc
    }
    #pragma unroll 2
    for (int ks = 0; ks < 8; ++ks) {
        int ko = ks * 32 + rg * 8;
        s16x8 wfr[4];
        #pragma unroll
        for (int nf = 0; nf < 4; ++nf)
            wfr[nf] = *(const s16x8*)(Ws + (nf * 16 + col) * HID + ko);
        s16x8 hfr[4];
        #pragma unroll
        for (int mf = 0; mf < 4; ++mf) {
            int m = mf * 16 + col;
            int byte = (m * 512 + ko * 2) ^ ((m & 7) << 4);
            hfr[mf] = *(const s16x8*)((const char*)hin + byte);
        }
        #pragma unroll
        for (int nf = 0; nf < 4; ++nf)
            #pragma unroll
            for (int mf = 0; mf < 4; ++mf)
                acc[nf][mf] = __builtin_amdgcn_mfma_f32_16x16x32_bf16(
                    wfr[nf], hfr[mf], acc[nf][mf], 0, 0, 0);
    }
    // epilogue: n = wid*64+nf*16+rg*4+r, m = mf*16+col
    #pragma unroll
    for (int nf = 0; nf < 4; ++nf) {
        int n0 = wid * 64 + nf * 16 + rg * 4;
        #pragma unroll
        for (int mf = 0; mf < 4; ++mf) {
            int m = mf * 16 + col;
            u32x2 w;
            w[0] = pack_bf2(fmaxf(acc[nf][mf][0], 0.f), fmaxf(acc[nf][mf][1], 0.f));
            w[1] = pack_bf2(fmaxf(acc[nf][mf][2], 0.f), fmaxf(acc[nf][mf][3], 0.f));
            int byte = (m * 512 + n0 * 2) ^ ((m & 7) << 4);
            *(u32x2*)((char*)hout + byte) = w;
        }
    }
}

// layer 2: unswapped mfma(h,W) -> D[m][n]; bias-in-acc; relu + pair-sum.
__device__ __forceinline__ void layer2_red(
        const unsigned short* __restrict__ Wl, const float* __restrict__ bias,
        const unsigned short* hin, float* pacc,
        int wid, int rg, int col) {
    const unsigned short* Ws = Wl + (size_t)(wid * 64) * HID;
    f32x4 acc[4][4];   // [mf][nf]
    #pragma unroll
    for (int nf = 0; nf < 4; ++nf) {
        float bv = bias[wid * 64 + nf * 16 + col];
        f32x4 bb = (f32x4){bv, bv, bv, bv};
        #pragma unroll
        for (int mf = 0; mf < 4; ++mf)
            acc[mf][nf] = bb;               // bias once per (m,n) element
    }
    #pragma unroll 2
    for (int ks = 0; ks < 8; ++ks) {
        int ko = ks * 32 + rg * 8;
        s16x8 wfr[4];
        #pragma unroll
        for (int nf = 0; nf < 4; ++nf)
            wfr[nf] = *(const s16x8*)(Ws + (nf * 16 + col) * HID + ko);
        s16x8 hfr[4];
        #pragma unroll
        for (int mf = 0; mf < 4; ++mf) {
            int m = mf * 16 + col;
            int byte = (m * 512 + ko * 2) ^ ((m & 7) << 4);
            hfr[mf] = *(const s16x8*)((const char*)hin + byte);
        }
        #pragma unroll
        for (int mf = 0; mf < 4; ++mf)
            #pragma unroll
            for (int nf = 0; nf < 4; ++nf)
                acc[mf][nf] = __builtin_amdgcn_mfma_f32_16x16x32_bf16(
                    hfr[mf], wfr[nf], acc[mf][nf], 0, 0, 0);
    }
    #pragma unroll
    for (int nf = 0; nf < 4; ++nf) {
        float s = 0.f;
        #pragma unroll
        for (int mf = 0; mf < 4; ++mf)
            #pragma unroll
            for (int r = 0; r < 4; ++r)
                s += fmaxf(acc[mf][nf][r], 0.f);
        s += __shfl_xor(s, 16);
        s += __shfl_xor(s, 32);
        pacc[nf] += s;
    }
}

// ---------------------------------------------------------------------------
// Kernel 2: main fused g-network. 256 threads = 4 waves, per-wave n-slice 64.
// Double-buffered h (2 x 32 KiB): epilogue writes the OTHER buffer, so only
// ONE barrier per layer (6 per WG vs 12). pp1's staging overlaps pp0's
// layer-2 K-loop (A cached in 32 regs from pp0 staging).
// Register cap: (256,2)=256; peak live ~190 (acc 64 + frags 64 + areg 32 +
// misc) -> >=60 slack (caps 128/170 spilled in r4/r5).
// ---------------------------------------------------------------------------
__global__ __launch_bounds__(256, 2) void rn_main(
        const unsigned short* __restrict__ Abf, const unsigned short* __restrict__ Bbf,
        const unsigned short* __restrict__ Wt,
        const float* __restrict__ g2_b, const float* __restrict__ g3_b,
        const float* __restrict__ g4_b, float* __restrict__ partial) {
    // XCD-aware swizzle: 2048 WGs, 8 XCDs (2048 % 8 == 0 -> bijective)
    int wg = blockIdx.x;
    int swz = (wg & 7) * 256 + (wg >> 3);
    int b = swz >> 5;
    int t = swz & 31;

    __shared__ unsigned short h0[D2 * HID];   // 32 KiB
    __shared__ unsigned short h1[D2 * HID];   // 32 KiB

    int tid = threadIdx.x;   // 0..255
    int lane = tid & 63;
    int wid = tid >> 6;      // wave 0..3 -> n-slice of 64
    int rg = lane >> 4;      // 0..3
    int col = lane & 15;

    const unsigned short* Ab  = Abf + (size_t)(b * D2) * HID;
    const unsigned short* Bb0 = Bbf + (size_t)(b * D2 + t * 2 + 0) * HID;
    const unsigned short* Bb1 = Bbf + (size_t)(b * D2 + t * 2 + 1) * HID;
    const unsigned short* W0 = Wt;
    const unsigned short* W1 = Wt + (size_t)1 * HID * HID;
    const unsigned short* W2 = Wt + (size_t)2 * HID * HID;

    s16x8 areg[8];                       // A slice cached across both pp
    float pacc[4] = {0.f, 0.f, 0.f, 0.f};

    // ---- pp0 ----
    stage_h<true>(h0, Bb0, areg, Ab, tid);
    __syncthreads();                               // h0 ready
    layer_sw(W0, g2_b, h0, h1, wid, rg, col);      // r h0 -> w h1
    __syncthreads();                               // h1 ready, h0 free
    layer_sw(W1, g3_b, h1, h0, wid, rg, col);      // r h1 -> w h0
    __syncthreads();                               // h0 ready, h1 free
    layer2_red(W2, g4_b, h0, pacc, wid, rg, col);  // r h0 (no LDS write)
    stage_h<false>(h1, Bb1, areg, Ab, tid);        // w h1 (overlaps layer2)
    __syncthreads();                               // h1 ready, h0 free

    // ---- pp1 (buffers flipped) ----
    layer_sw(W0, g2_b, h1, h0, wid, rg, col);
    __syncthreads();
    layer_sw(W1, g3_b, h0, h1, wid, rg, col);
    __syncthreads();
    layer2_red(W2, g4_b, h1, pacc, wid, rg, col);

    if (rg == 0) {
        #pragma unroll
        for (int nf = 0; nf < 4; ++nf)
            partial[(size_t)(b * NTILE + t) * HID + wid * 64 + nf * 16 + col]
                = pacc[nf];
    }
}

// ---------------------------------------------------------------------------
// Kernel 3: per-batch reduce over tiles + f-network (fp32) + log_softmax
// ---------------------------------------------------------------------------
__global__ __launch_bounds__(256) void fuse_kernel(
        const float* __restrict__ partial,
        const float* __restrict__ f1_w, const float* __restrict__ f1_b,
        const float* __restrict__ f2_w, const float* __restrict__ f2_b,
        const float* __restrict__ f3_w, const float* __restrict__ f3_b,
        float* __restrict__ out) {
    int b = blockIdx.x;
    int tid = threadIdx.x;
    __shared__ float xg[HID];
    __shared__ float h1[HID];
    __shared__ float h2[HID];
    __shared__ float lred[NOUT];
    __shared__ float lse;

    float s = 0.f;
    for (int t = 0; t < NTILE; ++t)
        s += partial[(size_t)(b * NTILE + t) * HID + tid];
    xg[tid] = s;
    __syncthreads();

    float a1 = f1_b[tid];
    for (int k = 0; k < HID; ++k)
        a1 += xg[k] * f1_w[k * HID + tid];
    h1[tid] = a1 > 0.f ? a1 : 0.f;
    __syncthreads();

    float a2 = f2_b[tid];
    for (int k = 0; k < HID; ++k)
        a2 += h1[k] * f2_w[k * HID + tid];
    h2[tid] = a2 > 0.f ? a2 : 0.f;
    __syncthreads();

    float logit = 0.f;
    if (tid < NOUT) {
        logit = f3_b[tid];
        for (int k = 0; k < HID; ++k)
            logit += h2[k] * f3_w[k * NOUT + tid];
        lred[tid] = logit;
    }
    __syncthreads();
    if (tid == 0) {
        float mx = lred[0];
        for (int j = 1; j < NOUT; ++j) mx = fmaxf(mx, lred[j]);
        float se = 0.f;
        for (int j = 0; j < NOUT; ++j) se += expf(lred[j] - mx);
        lse = mx + logf(se);
    }
    __syncthreads();
    if (tid < NOUT)
        out[b * NOUT + tid] = logit - lse;
}

// ---------------------------------------------------------------------------
extern "C" void kernel_launch(void* const* d_in, const int* in_sizes, int n_in,
                              void* d_out, int out_size, void* d_ws, size_t ws_size,
                              hipStream_t stream) {
    const float* x    = (const float*)d_in[0];
    const float* qst  = (const float*)d_in[1];
    const float* g1_w = (const float*)d_in[2];
    const float* g1_b = (const float*)d_in[3];
    const float* g2_w = (const float*)d_in[4];
    const float* g2_b = (const float*)d_in[5];
    const float* g3_w = (const float*)d_in[6];
    const float* g3_b = (const float*)d_in[7];
    const float* g4_w = (const float*)d_in[8];
    const float* g4_b = (const float*)d_in[9];
    const float* f1_w = (const float*)d_in[10];
    const float* f1_b = (const float*)d_in[11];
    const float* f2_w = (const float*)d_in[12];
    const float* f2_b = (const float*)d_in[13];
    const float* f3_w = (const float*)d_in[14];
    const float* f3_b = (const float*)d_in[15];
    float* out = (float*)d_out;

    char* ws = (char*)d_ws;
    unsigned short* Abf = (unsigned short*)ws;                          // 2 MiB
    unsigned short* Bbf = (unsigned short*)(ws + (2u << 20));           // 2 MiB
    unsigned short* Wt  = (unsigned short*)(ws + (4u << 20));           // 384 KiB
    float* partial      = (float*)(ws + (4u << 20) + (512u << 10));     // 2 MiB

    prep_all<<<768 + NB, 256, 0, stream>>>(x, qst, g1_w, g1_b, g2_w, g3_w, g4_w,
                                           Abf, Bbf, Wt);
    rn_main<<<NB * NTILE, 256, 0, stream>>>(Abf, Bbf, Wt, g2_b, g3_b, g4_b, partial);
    fuse_kernel<<<NB, 256, 0, stream>>>(partial, f1_w, f1_b, f2_w, f2_b, f3_w, f3_b, out);
}